// Round 4
// baseline (1693.695 us; speedup 1.0000x reference)
//
#include <hip/hip_runtime.h>

#define BATCH 8
#define NPTS 8192
#define NCH 64
#define NPOINT 1024
#define NSAMPLE 32

typedef float f4 __attribute__((ext_vector_type(4)));
typedef float f2 __attribute__((ext_vector_type(2)));

// ---------------------------------------------------------------------------
// Furthest point sampling: one block per batch, 1024 threads (16 waves).
// Sequential over 1024 picks; the per-iteration critical path is minimized:
//  - xyz staged in LDS (SoA, 96 KB): pivot fetch = broadcast ds_read, and
//    zero per-iter HBM traffic
//  - distance update as float2 pairs -> v_pk_add/mul_f32, contract(off)
//    keeps rounding identical to the reference (absmax 0.0 verified)
//  - local argmax: (val,idx) tree, ties keep left = lowest index
//  - full 6-step in-wave u64 butterfly -> 1 partial/wave (16 total,
//    parity double-buffered) -> ONE barrier -> every wave redundantly
//    reduces 16 partials (broadcast ds_read_b64 + 4-step butterfly).
//    No wave-0 serialization, no second barrier; waves drift/overlap.
//  - u64 key (dist_bits<<32)|~idx: max == float max with lowest-idx ties
//  - newxyz written once at the end from an LDS index list
// ---------------------------------------------------------------------------
__global__ __launch_bounds__(1024) void fps_kernel(const float* __restrict__ xyz,
                                                   float* __restrict__ newxyz) {
  const int b = blockIdx.x;
  const int tid = threadIdx.x;
  const int lane = tid & 63;
  const int wid = tid >> 6;  // 0..15
  const float* xb = xyz + (size_t)b * NPTS * 3;

  __shared__ float px_l[NPTS], py_l[NPTS], pz_l[NPTS];       // 96 KB SoA
  __shared__ __align__(16) unsigned long long pk[2][16];     // parity-buffered
  __shared__ unsigned short winidx[NPOINT];

  // Each thread owns 8 strided points as 4 float2 pairs, in registers;
  // also stages them into LDS for pivot lookups / final gather.
  f2 pxv[4], pyv[4], pzv[4], mindv[4];
#pragma unroll
  for (int j = 0; j < 4; ++j) {
    int p0 = tid + (2 * j) * 1024;
    int p1 = p0 + 1024;
    float x0 = xb[p0 * 3 + 0], y0 = xb[p0 * 3 + 1], z0 = xb[p0 * 3 + 2];
    float x1 = xb[p1 * 3 + 0], y1 = xb[p1 * 3 + 1], z1 = xb[p1 * 3 + 2];
    px_l[p0] = x0; py_l[p0] = y0; pz_l[p0] = z0;
    px_l[p1] = x1; py_l[p1] = y1; pz_l[p1] = z1;
    pxv[j] = f2{x0, x1};
    pyv[j] = f2{y0, y1};
    pzv[j] = f2{z0, z1};
    mindv[j] = f2{1e10f, 1e10f};
  }
  __syncthreads();

  float qx = px_l[0], qy = py_l[0], qz = pz_l[0];  // pivot = point 0

  for (int i = 1; i < NPOINT; ++i) {
#pragma clang fp contract(off)
    f2 qx2 = f2{qx, qx}, qy2 = f2{qy, qy}, qz2 = f2{qz, qz};

    float tv[8];
    unsigned int ti[8];
#pragma unroll
    for (int j = 0; j < 4; ++j) {
      f2 dx = pxv[j] - qx2;
      f2 dy = pyv[j] - qy2;
      f2 dz = pzv[j] - qz2;
      f2 d = (dx * dx + dy * dy) + dz * dz;  // same order/rounding as ref
      f2 m = mindv[j];
      m.x = fminf(m.x, d.x);
      m.y = fminf(m.y, d.y);
      mindv[j] = m;
      tv[2 * j + 0] = m.x; ti[2 * j + 0] = tid + (2 * j) * 1024;
      tv[2 * j + 1] = m.y; ti[2 * j + 1] = tid + (2 * j + 1) * 1024;
    }
    // local argmax tree (depth 3); strict > keeps left = lower index on ties
#pragma unroll
    for (int s = 1; s < 8; s <<= 1) {
#pragma unroll
      for (int j = 0; j < 8; j += 2 * s) {
        if (tv[j + s] > tv[j]) { tv[j] = tv[j + s]; ti[j] = ti[j + s]; }
      }
    }
    unsigned long long best =
        ((unsigned long long)__float_as_uint(tv[0]) << 32) |
        (unsigned long long)(~ti[0]);
    // full-wave butterfly (6 steps) -> every lane holds wave max
#pragma unroll
    for (int off = 32; off > 0; off >>= 1) {
      unsigned long long o = __shfl_xor(best, off);
      if (o > best) best = o;
    }
    const int par = i & 1;
    if (lane == 0) pk[par][wid] = best;
    __syncthreads();
    // every wave reduces the 16 partials in parallel (broadcast reads)
    unsigned long long r = pk[par][lane & 15];
#pragma unroll
    for (int off = 8; off > 0; off >>= 1) {
      unsigned long long o = __shfl_xor(r, off);
      if (o > r) r = o;
    }
    unsigned int idx = ~(unsigned int)r;  // identical on every thread
    if (tid == 0) winidx[i] = (unsigned short)idx;
    qx = px_l[idx];  // broadcast ds_read, no global traffic
    qy = py_l[idx];
    qz = pz_l[idx];
  }

  __syncthreads();
  // one pass writes all 1024 sampled points from LDS
  {
    const int idx = (tid == 0) ? 0 : (int)winidx[tid];
    float* op = newxyz + b * (NPOINT * 3) + tid * 3;
    op[0] = px_l[idx];
    op[1] = py_l[idx];
    op[2] = pz_l[idx];
  }
}

// ---------------------------------------------------------------------------
// Ball query: one wave per (b, s) center. Ordered scan, first 32 indices with
// d2 < r^2; pad with first hit (0 if none). Exact fp32 distance arithmetic.
// ---------------------------------------------------------------------------
__global__ __launch_bounds__(256) void ball_kernel(const float* __restrict__ xyz,
                                                   const float* __restrict__ newxyz,
                                                   int* __restrict__ idxout) {
  const int lane = threadIdx.x & 63;
  const int pair = blockIdx.x * 4 + (threadIdx.x >> 6);
  const int b = pair >> 10;
  const float cx = newxyz[pair * 3 + 0];
  const float cy = newxyz[pair * 3 + 1];
  const float cz = newxyz[pair * 3 + 2];
  const float* xb = xyz + (size_t)b * NPTS * 3;
  int* op = idxout + pair * NSAMPLE;

  int cnt = 0;
  int first = 0;
  for (int base = 0; base < NPTS && cnt < NSAMPLE; base += 64) {
    const int p = base + lane;
    const float* pp = xb + p * 3;
    float dx = __fsub_rn(cx, pp[0]);
    float dy = __fsub_rn(cy, pp[1]);
    float dz = __fsub_rn(cz, pp[2]);
    float d2 = __fadd_rn(__fadd_rn(__fmul_rn(dx, dx), __fmul_rn(dy, dy)),
                         __fmul_rn(dz, dz));
    bool pred = d2 < 0.04f;  // strict <, RADIUS^2 in fp32
    unsigned long long m = __ballot(pred);
    if (cnt == 0 && m) first = base + __builtin_ctzll(m);
    int rank = cnt + (int)__popcll(m & ((1ull << lane) - 1ull));
    if (pred && rank < NSAMPLE) op[rank] = p;
    cnt += (int)__popcll(m);
  }
  if (cnt < NSAMPLE) {
    for (int r = cnt + lane; r < NSAMPLE; r += 64) op[r] = first;
  }
}

// ---------------------------------------------------------------------------
// Group + 3-layer MLP + max-pool. One block (256 thr) per (b, s) group.
// Weights staged transposed in LDS (wt[c][o]) so o-lanes read coalesced b128;
// x rows read as b128 broadcast. Register tiles: 4o x 2n (L1/L2), 4o x 4n (L3).
// LDS: xa 32x68 + xb 32x64 + wt 8192 floats = 48.5 KB -> 3 blocks/CU.
// ---------------------------------------------------------------------------
__global__ __launch_bounds__(256) void group_mlp_kernel(
    const float* __restrict__ xyz, const float* __restrict__ feat,
    const float* __restrict__ w0, const float* __restrict__ s0, const float* __restrict__ b0,
    const float* __restrict__ w1, const float* __restrict__ s1, const float* __restrict__ b1,
    const float* __restrict__ w2, const float* __restrict__ s2, const float* __restrict__ b2,
    const int* __restrict__ idxin, const float* __restrict__ newxyz,
    float* __restrict__ outf) {
  __shared__ float xa[32][68];  // layer0 input (3 xyz + 64 feat + 1 zero pad)
  __shared__ float xb[32][64];  // layer1 out; reused as max-reduce buffer
  __shared__ float wt[8192];    // transposed weights of current layer

  const int tid = threadIdx.x;
  const int pair = blockIdx.x;
  const int b = pair >> 10;
  const int s = pair & 1023;

  // ---- gather: 8 threads per sample row ----
  {
    const float cx = newxyz[pair * 3 + 0];
    const float cy = newxyz[pair * 3 + 1];
    const float cz = newxyz[pair * 3 + 2];
    const int n = tid >> 3, k8 = tid & 7;
    const int pid = idxin[pair * NSAMPLE + n];
    const float* fr = feat + ((size_t)(b * NPTS) + pid) * NCH + k8 * 8;
    f4 f0 = *(const f4*)fr;
    f4 f1 = *(const f4*)(fr + 4);
#pragma unroll
    for (int q = 0; q < 4; ++q) xa[n][3 + k8 * 8 + q] = f0[q];
#pragma unroll
    for (int q = 0; q < 4; ++q) xa[n][3 + k8 * 8 + 4 + q] = f1[q];
    if (k8 == 0) {
      const float* pr = xyz + ((size_t)(b * NPTS) + pid) * 3;
      xa[n][0] = pr[0] - cx;
      xa[n][1] = pr[1] - cy;
      xa[n][2] = pr[2] - cz;
      xa[n][67] = 0.f;
    }
  }
  // stage wT0: wt[c*64+o] = w0[o][c], c in [0,68) (c==67 zero pad)
  for (int t = tid; t < 68 * 64; t += 256) {
    int c = t >> 6, o = t & 63;
    wt[t] = (c < 67) ? w0[o * 67 + c] : 0.f;
  }
  __syncthreads();

  // ---- layer 1: K=68(pad), 64 out; xa -> xb ----
  {
    const int ot = tid & 15, nt = tid >> 4;
    float acc[2][4] = {};
    for (int c = 0; c < 68; c += 4) {
      f4 xq0 = *(const f4*)&xa[nt * 2 + 0][c];
      f4 xq1 = *(const f4*)&xa[nt * 2 + 1][c];
#pragma unroll
      for (int cc = 0; cc < 4; ++cc) {
        f4 wq = *(const f4*)&wt[(c + cc) * 64 + ot * 4];
#pragma unroll
        for (int i = 0; i < 4; ++i) {
          acc[0][i] = fmaf(xq0[cc], wq[i], acc[0][i]);
          acc[1][i] = fmaf(xq1[cc], wq[i], acc[1][i]);
        }
      }
    }
    f4 r0, r1;
#pragma unroll
    for (int i = 0; i < 4; ++i) {
      float sc = s0[ot * 4 + i], bi = b0[ot * 4 + i];
      r0[i] = fmaxf(fmaf(acc[0][i], sc, bi), 0.f);
      r1[i] = fmaxf(fmaf(acc[1][i], sc, bi), 0.f);
    }
    *(f4*)&xb[nt * 2 + 0][ot * 4] = r0;
    *(f4*)&xb[nt * 2 + 1][ot * 4] = r1;
  }
  __syncthreads();
  for (int t = tid; t < 64 * 64; t += 256) {
    int c = t >> 6, o = t & 63;
    wt[t] = w1[o * 64 + c];
  }
  __syncthreads();

  // ---- layer 2: K=64, 64 out; xb -> xa ----
  {
    const int ot = tid & 15, nt = tid >> 4;
    float acc[2][4] = {};
    for (int c = 0; c < 64; c += 4) {
      f4 xq0 = *(const f4*)&xb[nt * 2 + 0][c];
      f4 xq1 = *(const f4*)&xb[nt * 2 + 1][c];
#pragma unroll
      for (int cc = 0; cc < 4; ++cc) {
        f4 wq = *(const f4*)&wt[(c + cc) * 64 + ot * 4];
#pragma unroll
        for (int i = 0; i < 4; ++i) {
          acc[0][i] = fmaf(xq0[cc], wq[i], acc[0][i]);
          acc[1][i] = fmaf(xq1[cc], wq[i], acc[1][i]);
        }
      }
    }
    f4 r0, r1;
#pragma unroll
    for (int i = 0; i < 4; ++i) {
      float sc = s1[ot * 4 + i], bi = b1[ot * 4 + i];
      r0[i] = fmaxf(fmaf(acc[0][i], sc, bi), 0.f);
      r1[i] = fmaxf(fmaf(acc[1][i], sc, bi), 0.f);
    }
    *(f4*)&xa[nt * 2 + 0][ot * 4] = r0;
    *(f4*)&xa[nt * 2 + 1][ot * 4] = r1;
  }
  __syncthreads();
  for (int t = tid; t < 64 * 128; t += 256) {
    int c = t >> 7, o = t & 127;
    wt[t] = w2[o * 64 + c];
  }
  __syncthreads();

  // ---- layer 3: K=64, 128 out; xa -> per-thread max over 4 n ----
  {
    const int ot = tid & 31, nt = tid >> 5;
    float acc[4][4] = {};
    for (int c = 0; c < 64; c += 4) {
      f4 xq[4];
#pragma unroll
      for (int j = 0; j < 4; ++j) xq[j] = *(const f4*)&xa[nt * 4 + j][c];
#pragma unroll
      for (int cc = 0; cc < 4; ++cc) {
        f4 wq = *(const f4*)&wt[(c + cc) * 128 + ot * 4];
#pragma unroll
        for (int j = 0; j < 4; ++j) {
#pragma unroll
          for (int i = 0; i < 4; ++i)
            acc[j][i] = fmaf(xq[j][cc], wq[i], acc[j][i]);
        }
      }
    }
    f4 mx;
#pragma unroll
    for (int i = 0; i < 4; ++i) {
      float sc = s2[ot * 4 + i], bi = b2[ot * 4 + i];
      float v0 = fmaxf(fmaf(acc[0][i], sc, bi), 0.f);
      float v1 = fmaxf(fmaf(acc[1][i], sc, bi), 0.f);
      float v2 = fmaxf(fmaf(acc[2][i], sc, bi), 0.f);
      float v3 = fmaxf(fmaf(acc[3][i], sc, bi), 0.f);
      mx[i] = fmaxf(fmaxf(v0, v1), fmaxf(v2, v3));
    }
    float* red = &xb[0][0];  // xb free after layer2 barrier
    *(f4*)&red[nt * 128 + ot * 4] = mx;
    __syncthreads();
    if (tid < 128) {
      float m = red[tid];
#pragma unroll
      for (int w = 1; w < 8; ++w) m = fmaxf(m, red[w * 128 + tid]);
      outf[((size_t)(b * 128 + tid)) * 1024 + s] = m;
    }
  }
}

extern "C" void kernel_launch(void* const* d_in, const int* in_sizes, int n_in,
                              void* d_out, int out_size, void* d_ws, size_t ws_size,
                              hipStream_t stream) {
  const float* xyz = (const float*)d_in[0];
  const float* feat = (const float*)d_in[1];
  const float* w0 = (const float*)d_in[2];
  const float* s0 = (const float*)d_in[3];
  const float* b0 = (const float*)d_in[4];
  const float* w1 = (const float*)d_in[5];
  const float* s1 = (const float*)d_in[6];
  const float* b1 = (const float*)d_in[7];
  const float* w2 = (const float*)d_in[8];
  const float* s2 = (const float*)d_in[9];
  const float* b2 = (const float*)d_in[10];

  float* newxyz = (float*)d_out;                    // (8,1024,3)
  float* outf = (float*)d_out + BATCH * NPOINT * 3; // (8,128,1024)
  int* idxws = (int*)d_ws;                          // (8*1024, 32) ints = 1 MB

  fps_kernel<<<BATCH, 1024, 0, stream>>>(xyz, newxyz);
  ball_kernel<<<(BATCH * NPOINT) / 4, 256, 0, stream>>>(xyz, newxyz, idxws);
  group_mlp_kernel<<<BATCH * NPOINT, 256, 0, stream>>>(
      xyz, feat, w0, s0, b0, w1, s1, b1, w2, s2, b2, idxws, newxyz, outf);
}

// Round 5
// 1520.846 us; speedup vs baseline: 1.1137x; 1.1137x over previous
//
#include <hip/hip_runtime.h>

#define BATCH 8
#define NPTS 8192
#define NCH 64
#define NPOINT 1024
#define NSAMPLE 32

typedef float f4 __attribute__((ext_vector_type(4)));
typedef float f2 __attribute__((ext_vector_type(2)));

// ---------------------------------------------------------------------------
// Furthest point sampling: one block per batch, 256 threads (4 waves, one per
// SIMD). Sequential over 1024 picks. R4 post-mortem: reduce machinery, not
// distance math, dominated issue (redundant per-wave (val,idx) trees + u64
// butterflies on 4 waves/SIMD). This version:
//  - thread t owns points [32t,32t+32) contiguously -> (thread,slot) order
//    equals global index order
//  - distance update: 16 f2 slots, v_pk ops, contract(off) => bitwise-exact
//    mind values (absmax 0.0 in R2-R4)
//  - VALUE-ONLY reduce: pk_max tree (15 insts) + 6-step f32 butterfly ->
//    4 wave partials -> barrier -> all read 4 floats -> gmax
//  - index recovery only on candidate threads (lmax==gmax, ~1/256): masked
//    scan for lowest matching slot + ds atomicMin of the global index.
//    Exactly reproduces argmax-first (lowest index) tie semantics.
//  - winslot double-buffered; reset after consumption; 2 barriers/iter
//  - xyz in LDS (SoA 96 KB) for pivot broadcast + final gather
// ---------------------------------------------------------------------------
__global__ __launch_bounds__(256) void fps_kernel(const float* __restrict__ xyz,
                                                  float* __restrict__ newxyz) {
  const int b = blockIdx.x;
  const int tid = threadIdx.x;
  const int lane = tid & 63;
  const int wid = tid >> 6;  // 0..3
  const float* xb = xyz + (size_t)b * NPTS * 3;

  __shared__ float px_l[NPTS], py_l[NPTS], pz_l[NPTS];  // 96 KB SoA
  __shared__ __align__(16) float pkv[2][4];             // wave partials
  __shared__ unsigned int winslot[2];
  __shared__ unsigned short winidx[NPOINT];

  const int base = tid * 32;
  f2 pxv[16], pyv[16], pzv[16], mindv[16];
#pragma unroll
  for (int j = 0; j < 16; ++j) {
    int p0 = base + 2 * j;
    int p1 = p0 + 1;
    float x0 = xb[p0 * 3 + 0], y0 = xb[p0 * 3 + 1], z0 = xb[p0 * 3 + 2];
    float x1 = xb[p1 * 3 + 0], y1 = xb[p1 * 3 + 1], z1 = xb[p1 * 3 + 2];
    px_l[p0] = x0; py_l[p0] = y0; pz_l[p0] = z0;
    px_l[p1] = x1; py_l[p1] = y1; pz_l[p1] = z1;
    pxv[j] = f2{x0, x1};
    pyv[j] = f2{y0, y1};
    pzv[j] = f2{z0, z1};
    mindv[j] = f2{1e10f, 1e10f};
  }
  if (tid == 0) { winslot[0] = 0xFFFFFFFFu; winslot[1] = 0xFFFFFFFFu; }
  __syncthreads();

  float qx = px_l[0], qy = py_l[0], qz = pz_l[0];  // pivot = point 0

  for (int i = 1; i < NPOINT; ++i) {
#pragma clang fp contract(off)
    const int par = i & 1;
    f2 qx2 = f2{qx, qx}, qy2 = f2{qy, qy}, qz2 = f2{qz, qz};

    // distance update (exact ref order) + value-only pk_max tree
    f2 tmax;
#pragma unroll
    for (int j = 0; j < 16; ++j) {
      f2 dx = pxv[j] - qx2;
      f2 dy = pyv[j] - qy2;
      f2 dz = pzv[j] - qz2;
      f2 d = (dx * dx + dy * dy) + dz * dz;
      f2 m = __builtin_elementwise_min(mindv[j], d);
      mindv[j] = m;
      tmax = (j == 0) ? m : __builtin_elementwise_max(tmax, m);
    }
    float lmax = fmaxf(tmax.x, tmax.y);
    // 6-step f32 butterfly -> wave max in every lane
    float wmax = lmax;
#pragma unroll
    for (int off = 32; off > 0; off >>= 1) {
      float o = __shfl_xor(wmax, off);
      wmax = fmaxf(wmax, o);
    }
    if (lane == 0) pkv[par][wid] = wmax;
    __syncthreads();
    f4 pv = *(const f4*)pkv[par];
    float gmax = fmaxf(fmaxf(pv[0], pv[1]), fmaxf(pv[2], pv[3]));

    // rare index recovery: lowest global index achieving gmax
    if (lmax == gmax) {
      int c = 0;
#pragma unroll
      for (int j = 15; j >= 0; --j) {
        if (mindv[j].y == gmax) c = 2 * j + 1;
        if (mindv[j].x == gmax) c = 2 * j;
      }
      atomicMin(&winslot[par], (unsigned int)(base + c));
    }
    __syncthreads();
    unsigned int idx = winslot[par];  // identical on every thread
    if (tid == 0) {
      winidx[i] = (unsigned short)idx;
      winslot[par ^ 1] = 0xFFFFFFFFu;  // reset buffer for iter i+1
    }
    qx = px_l[idx];  // broadcast ds_read
    qy = py_l[idx];
    qz = pz_l[idx];
  }

  __syncthreads();
  // write all 1024 sampled points from LDS
  for (int t = tid; t < NPOINT; t += 256) {
    const int idx = (t == 0) ? 0 : (int)winidx[t];
    float* op = newxyz + b * (NPOINT * 3) + t * 3;
    op[0] = px_l[idx];
    op[1] = py_l[idx];
    op[2] = pz_l[idx];
  }
}

// ---------------------------------------------------------------------------
// Ball query: one wave per (b, s) center. Ordered scan, first 32 indices with
// d2 < r^2; pad with first hit (0 if none). Exact fp32 distance arithmetic.
// ---------------------------------------------------------------------------
__global__ __launch_bounds__(256) void ball_kernel(const float* __restrict__ xyz,
                                                   const float* __restrict__ newxyz,
                                                   int* __restrict__ idxout) {
  const int lane = threadIdx.x & 63;
  const int pair = blockIdx.x * 4 + (threadIdx.x >> 6);
  const int b = pair >> 10;
  const float cx = newxyz[pair * 3 + 0];
  const float cy = newxyz[pair * 3 + 1];
  const float cz = newxyz[pair * 3 + 2];
  const float* xb = xyz + (size_t)b * NPTS * 3;
  int* op = idxout + pair * NSAMPLE;

  int cnt = 0;
  int first = 0;
  for (int base = 0; base < NPTS && cnt < NSAMPLE; base += 64) {
    const int p = base + lane;
    const float* pp = xb + p * 3;
    float dx = __fsub_rn(cx, pp[0]);
    float dy = __fsub_rn(cy, pp[1]);
    float dz = __fsub_rn(cz, pp[2]);
    float d2 = __fadd_rn(__fadd_rn(__fmul_rn(dx, dx), __fmul_rn(dy, dy)),
                         __fmul_rn(dz, dz));
    bool pred = d2 < 0.04f;  // strict <, RADIUS^2 in fp32
    unsigned long long m = __ballot(pred);
    if (cnt == 0 && m) first = base + __builtin_ctzll(m);
    int rank = cnt + (int)__popcll(m & ((1ull << lane) - 1ull));
    if (pred && rank < NSAMPLE) op[rank] = p;
    cnt += (int)__popcll(m);
  }
  if (cnt < NSAMPLE) {
    for (int r = cnt + lane; r < NSAMPLE; r += 64) op[r] = first;
  }
}

// ---------------------------------------------------------------------------
// Group + 3-layer MLP + max-pool. One block (256 thr) per (b, s) group.
// Weights staged transposed in LDS (wt[c][o]) so o-lanes read coalesced b128;
// x rows read as b128 broadcast. Register tiles: 4o x 2n (L1/L2), 4o x 4n (L3).
// LDS: xa 32x68 + xb 32x64 + wt 8192 floats = 48.5 KB -> 3 blocks/CU.
// ---------------------------------------------------------------------------
__global__ __launch_bounds__(256) void group_mlp_kernel(
    const float* __restrict__ xyz, const float* __restrict__ feat,
    const float* __restrict__ w0, const float* __restrict__ s0, const float* __restrict__ b0,
    const float* __restrict__ w1, const float* __restrict__ s1, const float* __restrict__ b1,
    const float* __restrict__ w2, const float* __restrict__ s2, const float* __restrict__ b2,
    const int* __restrict__ idxin, const float* __restrict__ newxyz,
    float* __restrict__ outf) {
  __shared__ float xa[32][68];  // layer0 input (3 xyz + 64 feat + 1 zero pad)
  __shared__ float xb[32][64];  // layer1 out; reused as max-reduce buffer
  __shared__ float wt[8192];    // transposed weights of current layer

  const int tid = threadIdx.x;
  const int pair = blockIdx.x;
  const int b = pair >> 10;
  const int s = pair & 1023;

  // ---- gather: 8 threads per sample row ----
  {
    const float cx = newxyz[pair * 3 + 0];
    const float cy = newxyz[pair * 3 + 1];
    const float cz = newxyz[pair * 3 + 2];
    const int n = tid >> 3, k8 = tid & 7;
    const int pid = idxin[pair * NSAMPLE + n];
    const float* fr = feat + ((size_t)(b * NPTS) + pid) * NCH + k8 * 8;
    f4 f0 = *(const f4*)fr;
    f4 f1 = *(const f4*)(fr + 4);
#pragma unroll
    for (int q = 0; q < 4; ++q) xa[n][3 + k8 * 8 + q] = f0[q];
#pragma unroll
    for (int q = 0; q < 4; ++q) xa[n][3 + k8 * 8 + 4 + q] = f1[q];
    if (k8 == 0) {
      const float* pr = xyz + ((size_t)(b * NPTS) + pid) * 3;
      xa[n][0] = pr[0] - cx;
      xa[n][1] = pr[1] - cy;
      xa[n][2] = pr[2] - cz;
      xa[n][67] = 0.f;
    }
  }
  // stage wT0: wt[c*64+o] = w0[o][c], c in [0,68) (c==67 zero pad)
  for (int t = tid; t < 68 * 64; t += 256) {
    int c = t >> 6, o = t & 63;
    wt[t] = (c < 67) ? w0[o * 67 + c] : 0.f;
  }
  __syncthreads();

  // ---- layer 1: K=68(pad), 64 out; xa -> xb ----
  {
    const int ot = tid & 15, nt = tid >> 4;
    float acc[2][4] = {};
    for (int c = 0; c < 68; c += 4) {
      f4 xq0 = *(const f4*)&xa[nt * 2 + 0][c];
      f4 xq1 = *(const f4*)&xa[nt * 2 + 1][c];
#pragma unroll
      for (int cc = 0; cc < 4; ++cc) {
        f4 wq = *(const f4*)&wt[(c + cc) * 64 + ot * 4];
#pragma unroll
        for (int i = 0; i < 4; ++i) {
          acc[0][i] = fmaf(xq0[cc], wq[i], acc[0][i]);
          acc[1][i] = fmaf(xq1[cc], wq[i], acc[1][i]);
        }
      }
    }
    f4 r0, r1;
#pragma unroll
    for (int i = 0; i < 4; ++i) {
      float sc = s0[ot * 4 + i], bi = b0[ot * 4 + i];
      r0[i] = fmaxf(fmaf(acc[0][i], sc, bi), 0.f);
      r1[i] = fmaxf(fmaf(acc[1][i], sc, bi), 0.f);
    }
    *(f4*)&xb[nt * 2 + 0][ot * 4] = r0;
    *(f4*)&xb[nt * 2 + 1][ot * 4] = r1;
  }
  __syncthreads();
  for (int t = tid; t < 64 * 64; t += 256) {
    int c = t >> 6, o = t & 63;
    wt[t] = w1[o * 64 + c];
  }
  __syncthreads();

  // ---- layer 2: K=64, 64 out; xb -> xa ----
  {
    const int ot = tid & 15, nt = tid >> 4;
    float acc[2][4] = {};
    for (int c = 0; c < 64; c += 4) {
      f4 xq0 = *(const f4*)&xb[nt * 2 + 0][c];
      f4 xq1 = *(const f4*)&xb[nt * 2 + 1][c];
#pragma unroll
      for (int cc = 0; cc < 4; ++cc) {
        f4 wq = *(const f4*)&wt[(c + cc) * 64 + ot * 4];
#pragma unroll
        for (int i = 0; i < 4; ++i) {
          acc[0][i] = fmaf(xq0[cc], wq[i], acc[0][i]);
          acc[1][i] = fmaf(xq1[cc], wq[i], acc[1][i]);
        }
      }
    }
    f4 r0, r1;
#pragma unroll
    for (int i = 0; i < 4; ++i) {
      float sc = s1[ot * 4 + i], bi = b1[ot * 4 + i];
      r0[i] = fmaxf(fmaf(acc[0][i], sc, bi), 0.f);
      r1[i] = fmaxf(fmaf(acc[1][i], sc, bi), 0.f);
    }
    *(f4*)&xa[nt * 2 + 0][ot * 4] = r0;
    *(f4*)&xa[nt * 2 + 1][ot * 4] = r1;
  }
  __syncthreads();
  for (int t = tid; t < 64 * 128; t += 256) {
    int c = t >> 7, o = t & 127;
    wt[t] = w2[o * 64 + c];
  }
  __syncthreads();

  // ---- layer 3: K=64, 128 out; xa -> per-thread max over 4 n ----
  {
    const int ot = tid & 31, nt = tid >> 5;
    float acc[4][4] = {};
    for (int c = 0; c < 64; c += 4) {
      f4 xq[4];
#pragma unroll
      for (int j = 0; j < 4; ++j) xq[j] = *(const f4*)&xa[nt * 4 + j][c];
#pragma unroll
      for (int cc = 0; cc < 4; ++cc) {
        f4 wq = *(const f4*)&wt[(c + cc) * 128 + ot * 4];
#pragma unroll
        for (int j = 0; j < 4; ++j) {
#pragma unroll
          for (int i = 0; i < 4; ++i)
            acc[j][i] = fmaf(xq[j][cc], wq[i], acc[j][i]);
        }
      }
    }
    f4 mx;
#pragma unroll
    for (int i = 0; i < 4; ++i) {
      float sc = s2[ot * 4 + i], bi = b2[ot * 4 + i];
      float v0 = fmaxf(fmaf(acc[0][i], sc, bi), 0.f);
      float v1 = fmaxf(fmaf(acc[1][i], sc, bi), 0.f);
      float v2 = fmaxf(fmaf(acc[2][i], sc, bi), 0.f);
      float v3 = fmaxf(fmaf(acc[3][i], sc, bi), 0.f);
      mx[i] = fmaxf(fmaxf(v0, v1), fmaxf(v2, v3));
    }
    float* red = &xb[0][0];  // xb free after layer2 barrier
    *(f4*)&red[nt * 128 + ot * 4] = mx;
    __syncthreads();
    if (tid < 128) {
      float m = red[tid];
#pragma unroll
      for (int w = 1; w < 8; ++w) m = fmaxf(m, red[w * 128 + tid]);
      outf[((size_t)(b * 128 + tid)) * 1024 + s] = m;
    }
  }
}

extern "C" void kernel_launch(void* const* d_in, const int* in_sizes, int n_in,
                              void* d_out, int out_size, void* d_ws, size_t ws_size,
                              hipStream_t stream) {
  const float* xyz = (const float*)d_in[0];
  const float* feat = (const float*)d_in[1];
  const float* w0 = (const float*)d_in[2];
  const float* s0 = (const float*)d_in[3];
  const float* b0 = (const float*)d_in[4];
  const float* w1 = (const float*)d_in[5];
  const float* s1 = (const float*)d_in[6];
  const float* b1 = (const float*)d_in[7];
  const float* w2 = (const float*)d_in[8];
  const float* s2 = (const float*)d_in[9];
  const float* b2 = (const float*)d_in[10];

  float* newxyz = (float*)d_out;                    // (8,1024,3)
  float* outf = (float*)d_out + BATCH * NPOINT * 3; // (8,128,1024)
  int* idxws = (int*)d_ws;                          // (8*1024, 32) ints = 1 MB

  fps_kernel<<<BATCH, 256, 0, stream>>>(xyz, newxyz);
  ball_kernel<<<(BATCH * NPOINT) / 4, 256, 0, stream>>>(xyz, newxyz, idxws);
  group_mlp_kernel<<<BATCH * NPOINT, 256, 0, stream>>>(
      xyz, feat, w0, s0, b0, w1, s1, b1, w2, s2, b2, idxws, newxyz, outf);
}

// Round 6
// 1420.663 us; speedup vs baseline: 1.1922x; 1.0705x over previous
//
#include <hip/hip_runtime.h>

#define BATCH 8
#define NPTS 8192
#define NCH 64
#define NPOINT 1024
#define NSAMPLE 32

typedef float f4 __attribute__((ext_vector_type(4)));
typedef float f2 __attribute__((ext_vector_type(2)));

// DPP-based u64 max step: merge with the value DPP-shifted across lanes.
// bound_ctrl=false + old=self => invalid-source lanes self-merge (no-op).
template <int CTRL>
__device__ __forceinline__ unsigned long long dpp_max_u64(unsigned long long k) {
  int lo = (int)(unsigned int)k;
  int hi = (int)(unsigned int)(k >> 32);
  int slo = __builtin_amdgcn_update_dpp(lo, lo, CTRL, 0xf, 0xf, false);
  int shi = __builtin_amdgcn_update_dpp(hi, hi, CTRL, 0xf, 0xf, false);
  unsigned long long s =
      ((unsigned long long)(unsigned int)shi << 32) | (unsigned int)slo;
  return (s > k) ? s : k;
}

// ---------------------------------------------------------------------------
// Furthest point sampling: one block per batch, 256 threads (4 waves, one per
// SIMD). R5 post-mortem: serial tail (bpermute shuffle chain + 2 barriers +
// atomics + dependent pivot loads) dominated. This version:
//  - interleaved ownership p = 2*tid + 512*j + k: LDS fill = ds_read_b64,
//    banks spread (2-way aliasing = free); staging coalesced (conflict-free)
//  - distance update: 16 f2 slots, v_pk ops, contract(off) -> bitwise-exact
//    mind values (absmax 0.0 R2-R5)
//  - value-only pk-max tree + thread-local scan for lowest matching global
//    index (j desc, y then x => lexicographic min); exact argmax-first ties
//  - wave argmax: 6 DPP u64-max steps (row_shr 1/2/4/8, row_bcast 15/31),
//    VALU speed, result in lane 63 — no ds_bpermute chain
//  - lane 63 writes {key, pivot coords} to parity-buffered LDS entry; ONE
//    barrier; all threads broadcast-read 4 entries, 3 u64 merges -> winner
//    key + coords directly (no post-barrier idx->coords load chain)
// ---------------------------------------------------------------------------
__global__ __launch_bounds__(256) void fps_kernel(const float* __restrict__ xyz,
                                                  float* __restrict__ newxyz) {
  const int b = blockIdx.x;
  const int tid = threadIdx.x;
  const int lane = tid & 63;
  const int wid = tid >> 6;  // 0..3
  const float* xb = xyz + (size_t)b * NPTS * 3;

  __shared__ float px_l[NPTS], py_l[NPTS], pz_l[NPTS];        // 96 KB SoA
  __shared__ __align__(16) unsigned long long pke[2][4][4];   // key, xy, z, pad
  __shared__ unsigned short winidx[NPOINT];

  // coalesced global -> LDS staging (lane-adjacent p => conflict-free writes)
  for (int p = tid; p < NPTS; p += 256) {
    px_l[p] = xb[p * 3 + 0];
    py_l[p] = xb[p * 3 + 1];
    pz_l[p] = xb[p * 3 + 2];
  }
  __syncthreads();

  // register fill from LDS: thread owns pairs (2t+512j, 2t+512j+1)
  f2 pxv[16], pyv[16], pzv[16], mindv[16];
#pragma unroll
  for (int j = 0; j < 16; ++j) {
    int p = 2 * tid + 512 * j;
    pxv[j] = *(const f2*)&px_l[p];
    pyv[j] = *(const f2*)&py_l[p];
    pzv[j] = *(const f2*)&pz_l[p];
    mindv[j] = f2{1e10f, 1e10f};
  }
  float qx = px_l[0], qy = py_l[0], qz = pz_l[0];  // pivot = point 0

  for (int i = 1; i < NPOINT; ++i) {
#pragma clang fp contract(off)
    const int par = i & 1;
    f2 qx2 = f2{qx, qx}, qy2 = f2{qy, qy}, qz2 = f2{qz, qz};

    // distance update (exact ref order) + value-only pk-max tree
    f2 tmax;
#pragma unroll
    for (int j = 0; j < 16; ++j) {
      f2 dx = pxv[j] - qx2;
      f2 dy = pyv[j] - qy2;
      f2 dz = pzv[j] - qz2;
      f2 d = (dx * dx + dy * dy) + dz * dz;
      f2 m = __builtin_elementwise_min(mindv[j], d);
      mindv[j] = m;
      tmax = (j == 0) ? m : __builtin_elementwise_max(tmax, m);
    }
    float lmax = fmaxf(tmax.x, tmax.y);

    // thread-local lowest global index achieving lmax
    // global idx = 2*tid + 512*j + k; scan j desc, y(k=1) then x(k=0)
    int c = 0;
#pragma unroll
    for (int j = 15; j >= 0; --j) {
      if (mindv[j].y == lmax) c = 2 * j + 1;
      if (mindv[j].x == lmax) c = 2 * j;
    }
    unsigned int gidx = (unsigned int)(2 * tid + ((c >> 1) << 9) + (c & 1));
    unsigned long long key =
        ((unsigned long long)__float_as_uint(lmax) << 32) |
        (unsigned long long)(~gidx);

    // wave argmax via DPP (VALU-speed), result valid in lane 63
    key = dpp_max_u64<0x111>(key);  // row_shr:1
    key = dpp_max_u64<0x112>(key);  // row_shr:2
    key = dpp_max_u64<0x114>(key);  // row_shr:4
    key = dpp_max_u64<0x118>(key);  // row_shr:8
    key = dpp_max_u64<0x142>(key);  // row_bcast:15
    key = dpp_max_u64<0x143>(key);  // row_bcast:31

    if (lane == 63) {
      unsigned int widx = ~(unsigned int)key;
      float wx = px_l[widx], wy = py_l[widx], wz = pz_l[widx];
      ulonglong2 e0;
      e0.x = key;
      e0.y = ((unsigned long long)__float_as_uint(wy) << 32) |
             (unsigned long long)__float_as_uint(wx);
      *(ulonglong2*)&pke[par][wid][0] = e0;
      pke[par][wid][2] = (unsigned long long)__float_as_uint(wz);
    }
    __syncthreads();

    // merge the 4 wave entries (broadcast LDS reads, b128)
    const ulonglong2* ew = (const ulonglong2*)&pke[par][0][0];
    ulonglong2 m0 = ew[0];                 // {key, xy}
    unsigned long long bz = ew[1].x;       // {z, pad}
#pragma unroll
    for (int w = 1; w < 4; ++w) {
      ulonglong2 t = ew[2 * w];
      unsigned long long tz = ew[2 * w + 1].x;
      if (t.x > m0.x) { m0 = t; bz = tz; }
    }
    qx = __uint_as_float((unsigned int)m0.y);
    qy = __uint_as_float((unsigned int)(m0.y >> 32));
    qz = __uint_as_float((unsigned int)bz);
    if (tid == 0) winidx[i] = (unsigned short)(~(unsigned int)m0.x);
  }

  __syncthreads();
  // write all 1024 sampled points from LDS
  for (int t = tid; t < NPOINT; t += 256) {
    const int idx = (t == 0) ? 0 : (int)winidx[t];
    float* op = newxyz + b * (NPOINT * 3) + t * 3;
    op[0] = px_l[idx];
    op[1] = py_l[idx];
    op[2] = pz_l[idx];
  }
}

// ---------------------------------------------------------------------------
// Ball query: one wave per (b, s) center. Ordered scan, first 32 indices with
// d2 < r^2; pad with first hit (0 if none). Exact fp32 distance arithmetic.
// ---------------------------------------------------------------------------
__global__ __launch_bounds__(256) void ball_kernel(const float* __restrict__ xyz,
                                                   const float* __restrict__ newxyz,
                                                   int* __restrict__ idxout) {
  const int lane = threadIdx.x & 63;
  const int pair = blockIdx.x * 4 + (threadIdx.x >> 6);
  const int b = pair >> 10;
  const float cx = newxyz[pair * 3 + 0];
  const float cy = newxyz[pair * 3 + 1];
  const float cz = newxyz[pair * 3 + 2];
  const float* xb = xyz + (size_t)b * NPTS * 3;
  int* op = idxout + pair * NSAMPLE;

  int cnt = 0;
  int first = 0;
  for (int base = 0; base < NPTS && cnt < NSAMPLE; base += 64) {
    const int p = base + lane;
    const float* pp = xb + p * 3;
    float dx = __fsub_rn(cx, pp[0]);
    float dy = __fsub_rn(cy, pp[1]);
    float dz = __fsub_rn(cz, pp[2]);
    float d2 = __fadd_rn(__fadd_rn(__fmul_rn(dx, dx), __fmul_rn(dy, dy)),
                         __fmul_rn(dz, dz));
    bool pred = d2 < 0.04f;  // strict <, RADIUS^2 in fp32
    unsigned long long m = __ballot(pred);
    if (cnt == 0 && m) first = base + __builtin_ctzll(m);
    int rank = cnt + (int)__popcll(m & ((1ull << lane) - 1ull));
    if (pred && rank < NSAMPLE) op[rank] = p;
    cnt += (int)__popcll(m);
  }
  if (cnt < NSAMPLE) {
    for (int r = cnt + lane; r < NSAMPLE; r += 64) op[r] = first;
  }
}

// ---------------------------------------------------------------------------
// Group + 3-layer MLP + max-pool. One block (256 thr) per (b, s) group.
// Weights staged transposed in LDS (wt[c][o]) so o-lanes read coalesced b128;
// x rows read as b128 broadcast. Register tiles: 4o x 2n (L1/L2), 4o x 4n (L3).
// LDS: xa 32x68 + xb 32x64 + wt 8192 floats = 48.5 KB -> 3 blocks/CU.
// ---------------------------------------------------------------------------
__global__ __launch_bounds__(256) void group_mlp_kernel(
    const float* __restrict__ xyz, const float* __restrict__ feat,
    const float* __restrict__ w0, const float* __restrict__ s0, const float* __restrict__ b0,
    const float* __restrict__ w1, const float* __restrict__ s1, const float* __restrict__ b1,
    const float* __restrict__ w2, const float* __restrict__ s2, const float* __restrict__ b2,
    const int* __restrict__ idxin, const float* __restrict__ newxyz,
    float* __restrict__ outf) {
  __shared__ float xa[32][68];  // layer0 input (3 xyz + 64 feat + 1 zero pad)
  __shared__ float xb[32][64];  // layer1 out; reused as max-reduce buffer
  __shared__ float wt[8192];    // transposed weights of current layer

  const int tid = threadIdx.x;
  const int pair = blockIdx.x;
  const int b = pair >> 10;
  const int s = pair & 1023;

  // ---- gather: 8 threads per sample row ----
  {
    const float cx = newxyz[pair * 3 + 0];
    const float cy = newxyz[pair * 3 + 1];
    const float cz = newxyz[pair * 3 + 2];
    const int n = tid >> 3, k8 = tid & 7;
    const int pid = idxin[pair * NSAMPLE + n];
    const float* fr = feat + ((size_t)(b * NPTS) + pid) * NCH + k8 * 8;
    f4 f0 = *(const f4*)fr;
    f4 f1 = *(const f4*)(fr + 4);
#pragma unroll
    for (int q = 0; q < 4; ++q) xa[n][3 + k8 * 8 + q] = f0[q];
#pragma unroll
    for (int q = 0; q < 4; ++q) xa[n][3 + k8 * 8 + 4 + q] = f1[q];
    if (k8 == 0) {
      const float* pr = xyz + ((size_t)(b * NPTS) + pid) * 3;
      xa[n][0] = pr[0] - cx;
      xa[n][1] = pr[1] - cy;
      xa[n][2] = pr[2] - cz;
      xa[n][67] = 0.f;
    }
  }
  // stage wT0: wt[c*64+o] = w0[o][c], c in [0,68) (c==67 zero pad)
  for (int t = tid; t < 68 * 64; t += 256) {
    int c = t >> 6, o = t & 63;
    wt[t] = (c < 67) ? w0[o * 67 + c] : 0.f;
  }
  __syncthreads();

  // ---- layer 1: K=68(pad), 64 out; xa -> xb ----
  {
    const int ot = tid & 15, nt = tid >> 4;
    float acc[2][4] = {};
    for (int c = 0; c < 68; c += 4) {
      f4 xq0 = *(const f4*)&xa[nt * 2 + 0][c];
      f4 xq1 = *(const f4*)&xa[nt * 2 + 1][c];
#pragma unroll
      for (int cc = 0; cc < 4; ++cc) {
        f4 wq = *(const f4*)&wt[(c + cc) * 64 + ot * 4];
#pragma unroll
        for (int i = 0; i < 4; ++i) {
          acc[0][i] = fmaf(xq0[cc], wq[i], acc[0][i]);
          acc[1][i] = fmaf(xq1[cc], wq[i], acc[1][i]);
        }
      }
    }
    f4 r0, r1;
#pragma unroll
    for (int i = 0; i < 4; ++i) {
      float sc = s0[ot * 4 + i], bi = b0[ot * 4 + i];
      r0[i] = fmaxf(fmaf(acc[0][i], sc, bi), 0.f);
      r1[i] = fmaxf(fmaf(acc[1][i], sc, bi), 0.f);
    }
    *(f4*)&xb[nt * 2 + 0][ot * 4] = r0;
    *(f4*)&xb[nt * 2 + 1][ot * 4] = r1;
  }
  __syncthreads();
  for (int t = tid; t < 64 * 64; t += 256) {
    int c = t >> 6, o = t & 63;
    wt[t] = w1[o * 64 + c];
  }
  __syncthreads();

  // ---- layer 2: K=64, 64 out; xb -> xa ----
  {
    const int ot = tid & 15, nt = tid >> 4;
    float acc[2][4] = {};
    for (int c = 0; c < 64; c += 4) {
      f4 xq0 = *(const f4*)&xb[nt * 2 + 0][c];
      f4 xq1 = *(const f4*)&xb[nt * 2 + 1][c];
#pragma unroll
      for (int cc = 0; cc < 4; ++cc) {
        f4 wq = *(const f4*)&wt[(c + cc) * 64 + ot * 4];
#pragma unroll
        for (int i = 0; i < 4; ++i) {
          acc[0][i] = fmaf(xq0[cc], wq[i], acc[0][i]);
          acc[1][i] = fmaf(xq1[cc], wq[i], acc[1][i]);
        }
      }
    }
    f4 r0, r1;
#pragma unroll
    for (int i = 0; i < 4; ++i) {
      float sc = s1[ot * 4 + i], bi = b1[ot * 4 + i];
      r0[i] = fmaxf(fmaf(acc[0][i], sc, bi), 0.f);
      r1[i] = fmaxf(fmaf(acc[1][i], sc, bi), 0.f);
    }
    *(f4*)&xa[nt * 2 + 0][ot * 4] = r0;
    *(f4*)&xa[nt * 2 + 1][ot * 4] = r1;
  }
  __syncthreads();
  for (int t = tid; t < 64 * 128; t += 256) {
    int c = t >> 7, o = t & 127;
    wt[t] = w2[o * 64 + c];
  }
  __syncthreads();

  // ---- layer 3: K=64, 128 out; xa -> per-thread max over 4 n ----
  {
    const int ot = tid & 31, nt = tid >> 5;
    float acc[4][4] = {};
    for (int c = 0; c < 64; c += 4) {
      f4 xq[4];
#pragma unroll
      for (int j = 0; j < 4; ++j) xq[j] = *(const f4*)&xa[nt * 4 + j][c];
#pragma unroll
      for (int cc = 0; cc < 4; ++cc) {
        f4 wq = *(const f4*)&wt[(c + cc) * 128 + ot * 4];
#pragma unroll
        for (int j = 0; j < 4; ++j) {
#pragma unroll
          for (int i = 0; i < 4; ++i)
            acc[j][i] = fmaf(xq[j][cc], wq[i], acc[j][i]);
        }
      }
    }
    f4 mx;
#pragma unroll
    for (int i = 0; i < 4; ++i) {
      float sc = s2[ot * 4 + i], bi = b2[ot * 4 + i];
      float v0 = fmaxf(fmaf(acc[0][i], sc, bi), 0.f);
      float v1 = fmaxf(fmaf(acc[1][i], sc, bi), 0.f);
      float v2 = fmaxf(fmaf(acc[2][i], sc, bi), 0.f);
      float v3 = fmaxf(fmaf(acc[3][i], sc, bi), 0.f);
      mx[i] = fmaxf(fmaxf(v0, v1), fmaxf(v2, v3));
    }
    float* red = &xb[0][0];  // xb free after layer2 barrier
    *(f4*)&red[nt * 128 + ot * 4] = mx;
    __syncthreads();
    if (tid < 128) {
      float m = red[tid];
#pragma unroll
      for (int w = 1; w < 8; ++w) m = fmaxf(m, red[w * 128 + tid]);
      outf[((size_t)(b * 128 + tid)) * 1024 + s] = m;
    }
  }
}

extern "C" void kernel_launch(void* const* d_in, const int* in_sizes, int n_in,
                              void* d_out, int out_size, void* d_ws, size_t ws_size,
                              hipStream_t stream) {
  const float* xyz = (const float*)d_in[0];
  const float* feat = (const float*)d_in[1];
  const float* w0 = (const float*)d_in[2];
  const float* s0 = (const float*)d_in[3];
  const float* b0 = (const float*)d_in[4];
  const float* w1 = (const float*)d_in[5];
  const float* s1 = (const float*)d_in[6];
  const float* b1 = (const float*)d_in[7];
  const float* w2 = (const float*)d_in[8];
  const float* s2 = (const float*)d_in[9];
  const float* b2 = (const float*)d_in[10];

  float* newxyz = (float*)d_out;                    // (8,1024,3)
  float* outf = (float*)d_out + BATCH * NPOINT * 3; // (8,128,1024)
  int* idxws = (int*)d_ws;                          // (8*1024, 32) ints = 1 MB

  fps_kernel<<<BATCH, 256, 0, stream>>>(xyz, newxyz);
  ball_kernel<<<(BATCH * NPOINT) / 4, 256, 0, stream>>>(xyz, newxyz, idxws);
  group_mlp_kernel<<<BATCH * NPOINT, 256, 0, stream>>>(
      xyz, feat, w0, s0, b0, w1, s1, b1, w2, s2, b2, idxws, newxyz, outf);
}